// Round 2
// baseline (1711.516 us; speedup 1.0000x reference)
//
#include <hip/hip_runtime.h>
#include <cstdint>
#include <math.h>

#define IN_FEAT 320
#define OUT_FEAT 2048
#define NB 8
#define KSIL 320
#define KTOT 2880          // 320 silu + 2560 spline-basis columns
#define BM 128
#define BN 128
#define BK 32
#define NT (KTOT / BK)     // 90 K-steps
#define LDA 40             // tier-2 fallback LDS stride
#define BN_EPS 1e-3f
#define A_OFF ((size_t)16 << 20)   // A starts 16 MB into d_ws (W lives below)

typedef __bf16 bf16;
typedef __attribute__((ext_vector_type(8))) __bf16 bf16x8;
typedef __attribute__((ext_vector_type(4))) float f32x4;

#define VMW(n) asm volatile("s_waitcnt vmcnt(" #n ")" ::: "memory")
#define BAR() __builtin_amdgcn_s_barrier()

// Uniform cubic B-spline closed form == reference Cox-de Boor recursion.
__device__ __forceinline__ void bspline8(float xv, float* b) {
    float xc = (xv + 2.2f) * 2.5f;
    float cf = floorf(xc);
    int c = (int)cf;
    float t = xc - cf;
    float omt = 1.0f - t;
    float t2 = t * t, t3 = t2 * t;
    float w0 = omt * omt * omt * (1.0f / 6.0f);
    float w1 = (3.0f * t3 - 6.0f * t2 + 4.0f) * (1.0f / 6.0f);
    float w2 = (-3.0f * t3 + 3.0f * t2 + 3.0f * t + 1.0f) * (1.0f / 6.0f);
    float w3 = t3 * (1.0f / 6.0f);
    if (xc < 0.0f) { w0 = w1 = w2 = w3 = 0.0f; }
#pragma unroll
    for (int j = 0; j < 8; ++j) {
        int d = c - j;
        b[j] = (d == 3) ? w0 : (d == 2) ? w1 : (d == 1) ? w2 : (d == 0) ? w3 : 0.0f;
    }
}

__device__ __forceinline__ bf16x8 pack8(const float* f) {
    bf16x8 v;
#pragma unroll
    for (int j = 0; j < 8; ++j) v[j] = (bf16)f[j];
    return v;
}

__device__ __forceinline__ void gl2lds16(const bf16* g, bf16* l) {
    __builtin_amdgcn_global_load_lds(
        (const __attribute__((address_space(1))) void*)g,
        (__attribute__((address_space(3))) void*)l, 16, 0, 0);
}

// Fuse W = [base_weight | spline_weight*scaler] -> bf16, k-major W[o][2880].
__global__ __launch_bounds__(256) void prep_w(const float* __restrict__ bw,
                                              const float* __restrict__ sw,
                                              const float* __restrict__ ss,
                                              bf16* __restrict__ W) {
    const int k = blockIdx.x * 256 + threadIdx.x;
    const int o = blockIdx.y;
    if (k >= KTOT) return;
    float w;
    if (k < KSIL) {
        w = bw[o * IN_FEAT + k];
    } else {
        const int s = k - KSIL;
        const int i = s >> 3, j = s & 7;
        w = sw[(o * IN_FEAT + i) * NB + j] * ss[o * IN_FEAT + i];
    }
    W[o * KTOT + k] = (bf16)w;
}

// Precompute A = [silu(x) | bases(x)] bf16, k-major A[row][2880].
__global__ __launch_bounds__(256) void prep_a(const float* __restrict__ x,
                                              bf16* __restrict__ A, int total) {
    const int t = blockIdx.x * 256 + threadIdx.x;
    if (t >= total) return;
    const int row = t / IN_FEAT;
    const int f = t - row * IN_FEAT;
    const float xv = x[t];
    A[(size_t)row * KTOT + f] = (bf16)(xv / (1.0f + __expf(-xv)));
    float b[8];
    bspline8(xv, b);
    *(bf16x8*)&A[(size_t)row * KTOT + KSIL + f * 8] = pack8(b);
}

// Tier-1: pure GEMM from precomputed A (ws) and W (ws).
// 3-buffer LDS pipeline, 2 K-steps of global_load_lds prefetch in flight,
// counted vmcnt(8) (never drain to 0 in main loop), setprio around MFMA,
// XOR-swizzled LDS layout, fused linear-path/BN/ReLU epilogue.
__global__ __launch_bounds__(256)
void pfn_gemm_ws(const float* __restrict__ x, const bf16* __restrict__ A,
                 const bf16* __restrict__ W, const float* __restrict__ lw,
                 const float* __restrict__ gamma, const float* __restrict__ beta,
                 const float* __restrict__ mean, const float* __restrict__ var,
                 float* __restrict__ out, int N, int nbx) {
    __shared__ bf16 As[3][BM * BK];   // 3 x 8 KB
    __shared__ bf16 Bs[3][BN * BK];   // 3 x 8 KB  (48 KB total -> 3 blocks/CU)

    // super-tile remap: 32 bx-tiles x 16 by-tiles per group (A slab L3-hot)
    const int blk = blockIdx.x;
    const int sid = blk >> 9;
    const int tt = blk & 511;
    const int by = tt >> 5;
    const int bx = (sid << 5) + (tt & 31);
    if (bx >= nbx) return;

    const int row0 = bx * BM;
    const int col0 = by * BN;
    const int tid = threadIdx.x;
    const int wave = tid >> 6;
    const int lane = tid & 63;
    const int wr = wave >> 1;
    const int wc = wave & 1;
    const int l15 = lane & 15;
    const int quad = lane >> 4;

    // staging: thread owns 16-B chunks tid and tid+256 of each tile.
    // chunk q -> LDS byte q*16, holds row r=q>>2, k-group g = (q&3)^((r>>1)&3)
    const int r0 = tid >> 2;
    const int s0 = tid & 3;
    const int g0 = s0 ^ ((r0 >> 1) & 3);
    const bf16* a0 = A + (size_t)(row0 + r0) * KTOT + g0 * 8;
    const bf16* a1 = a0 + (size_t)64 * KTOT;
    const bf16* b0 = W + (size_t)(col0 + r0) * KTOT + g0 * 8;
    const bf16* b1 = b0 + (size_t)64 * KTOT;

    // fragment-read swizzle slot (same formula: row low bits == l15 low bits)
    const int sfr = quad ^ ((l15 >> 1) & 3);

    f32x4 acc[4][4] = {};

    auto stage = [&](int b, int kc) {
        gl2lds16(a0 + kc, &As[b][tid * 8]);
        gl2lds16(a1 + kc, &As[b][(tid + 256) * 8]);
        gl2lds16(b0 + kc, &Bs[b][tid * 8]);
        gl2lds16(b1 + kc, &Bs[b][(tid + 256) * 8]);
    };
    auto step = [&](int b) {
        bf16x8 af[4], bv[4];
#pragma unroll
        for (int i = 0; i < 4; ++i)
            af[i] = *(const bf16x8*)&As[b][(wr * 64 + i * 16 + l15) * BK + sfr * 8];
#pragma unroll
        for (int j = 0; j < 4; ++j)
            bv[j] = *(const bf16x8*)&Bs[b][(wc * 64 + j * 16 + l15) * BK + sfr * 8];
        __builtin_amdgcn_s_setprio(1);
#pragma unroll
        for (int i = 0; i < 4; ++i)
#pragma unroll
            for (int j = 0; j < 4; ++j)
                acc[i][j] = __builtin_amdgcn_mfma_f32_16x16x32_bf16(af[i], bv[j],
                                                                   acc[i][j], 0, 0, 0);
        __builtin_amdgcn_s_setprio(0);
    };

    // prologue: tiles 0,1 in flight
    stage(0, 0);
    stage(1, BK);

    // main: 29 groups of 3 steps (tiles 0..86); each step stages tile t+2,
    // waits only the 4 oldest loads (vmcnt(8) leaves tiles t+1,t+2 in flight)
    int kc = 0;
#pragma unroll 1
    for (int u = 0; u < NT / 3 - 1; ++u) {
        stage(2, kc + 2 * BK); VMW(8); BAR();
        step(0); BAR();
        stage(0, kc + 3 * BK); VMW(8); BAR();
        step(1); BAR();
        stage(1, kc + 4 * BK); VMW(8); BAR();
        step(2); BAR();
        kc += 3 * BK;
    }
    // tail: tiles 87 (buf0), 88 (buf1), 89 (buf2); kc == 87*BK here
    stage(2, kc + 2 * BK); VMW(8); BAR();
    step(0); BAR();
    VMW(4); BAR();
    step(1); BAR();
    VMW(0); BAR();
    step(2);

    // epilogue: + linear path, BN, ReLU, store
    const int p = by * 2 + wc;
    float sc[4], sh[4];
#pragma unroll
    for (int j = 0; j < 4; ++j) {
        const int c = j * 16 + l15;
        const float s = rsqrtf(var[c] + BN_EPS) * gamma[c];
        sc[j] = s;
        sh[j] = beta[c] - mean[c] * s;
    }
#pragma unroll
    for (int i = 0; i < 4; ++i) {
#pragma unroll
        for (int reg = 0; reg < 4; ++reg) {
            const int row = row0 + wr * 64 + i * 16 + quad * 4 + reg;
            if (row >= N) continue;
            float xq[10];
            const float* xp = &x[(size_t)row * IN_FEAT + p * 10];
#pragma unroll
            for (int q = 0; q < 10; ++q) xq[q] = xp[q];
#pragma unroll
            for (int j = 0; j < 4; ++j) {
                const int c = j * 16 + l15;
                float v = acc[i][j][reg];
#pragma unroll
                for (int q = 0; q < 10; ++q) v = fmaf(xq[q], lw[c * 10 + q], v);
                v = fmaxf(v * sc[j] + sh[j], 0.0f);
                out[((size_t)row * 32 + p) * 128 + c] = v;
            }
        }
    }
}

// ---- Tier-2/0 fallback: round-2 fused kernel (known-correct) ----
template <bool HASW>
__global__ __launch_bounds__(256)
void pfn_gemm(const float* __restrict__ x, const bf16* __restrict__ W,
              const float* __restrict__ bw, const float* __restrict__ sw,
              const float* __restrict__ ss, const float* __restrict__ lw,
              const float* __restrict__ gamma, const float* __restrict__ beta,
              const float* __restrict__ mean, const float* __restrict__ var,
              float* __restrict__ out, int N) {
    __shared__ bf16 As[BM * LDA];
    __shared__ bf16 Bs[BN * LDA];
    const int tid = threadIdx.x;
    const int row0 = blockIdx.x * BM;
    const int col0 = blockIdx.y * BN;
    const int wave = tid >> 6;
    const int lane = tid & 63;
    const int wr = wave >> 1;
    const int wc = wave & 1;
    const int l15 = lane & 15;
    const int quad = lane >> 4;
    f32x4 acc[4][4] = {};
    auto stage_b = [&](int kc) {
        const int ol = tid >> 1;
        const int k0 = (tid & 1) * 16;
        if (HASW) {
            const bf16x8* src = (const bf16x8*)&W[(size_t)(col0 + ol) * KTOT + kc + k0];
            *(bf16x8*)&Bs[ol * LDA + k0] = src[0];
            *(bf16x8*)&Bs[ol * LDA + k0 + 8] = src[1];
        } else {
            const int o = col0 + ol;
#pragma unroll
            for (int u = 0; u < 16; ++u) {
                const int gk = kc + k0 + u;
                float w;
                if (gk < KSIL) {
                    w = bw[o * IN_FEAT + gk];
                } else {
                    const int s = gk - KSIL;
                    const int i = s >> 3, j = s & 7;
                    w = sw[(o * IN_FEAT + i) * NB + j] * ss[o * IN_FEAT + i];
                }
                Bs[ol * LDA + k0 + u] = (bf16)w;
            }
        }
    };
    auto mma_step = [&]() {
        bf16x8 af[4], bv[4];
#pragma unroll
        for (int i = 0; i < 4; ++i)
            af[i] = *(const bf16x8*)&As[(wr * 64 + i * 16 + l15) * LDA + quad * 8];
#pragma unroll
        for (int j = 0; j < 4; ++j)
            bv[j] = *(const bf16x8*)&Bs[(wc * 64 + j * 16 + l15) * LDA + quad * 8];
#pragma unroll
        for (int i = 0; i < 4; ++i)
#pragma unroll
            for (int j = 0; j < 4; ++j)
                acc[i][j] = __builtin_amdgcn_mfma_f32_16x16x32_bf16(af[i], bv[j],
                                                                   acc[i][j], 0, 0, 0);
    };
    for (int kc = 0; kc < KSIL; kc += BK) {
        __syncthreads();
        stage_b(kc);
        {
            const int r = tid >> 1;
            const int k0 = (tid & 1) * 16;
            const int row = row0 + r;
            float v[16];
            if (row < N) {
                const float* xp = &x[(size_t)row * IN_FEAT + kc + k0];
#pragma unroll
                for (int u = 0; u < 16; ++u) {
                    const float xv = xp[u];
                    v[u] = xv / (1.0f + __expf(-xv));
                }
            } else {
#pragma unroll
                for (int u = 0; u < 16; ++u) v[u] = 0.0f;
            }
            *(bf16x8*)&As[r * LDA + k0] = pack8(v);
            *(bf16x8*)&As[r * LDA + k0 + 8] = pack8(v + 8);
        }
        __syncthreads();
        mma_step();
    }
    for (int kc = KSIL; kc < KTOT; kc += BK) {
        __syncthreads();
        stage_b(kc);
        {
            const int i0 = (kc - KSIL) >> 3;
#pragma unroll
            for (int s = 0; s < 2; ++s) {
                const int task = tid + s * 256;
                const int r = task >> 2;
                const int f = task & 3;
                const int row = row0 + r;
                float b[8];
                if (row < N) {
                    bspline8(x[(size_t)row * IN_FEAT + i0 + f], b);
                } else {
#pragma unroll
                    for (int j = 0; j < 8; ++j) b[j] = 0.0f;
                }
                *(bf16x8*)&As[r * LDA + f * 8] = pack8(b);
            }
        }
        __syncthreads();
        mma_step();
    }
    const int p = blockIdx.y * 2 + wc;
    float sc[4], sh[4];
#pragma unroll
    for (int j = 0; j < 4; ++j) {
        const int c = j * 16 + l15;
        const float s = rsqrtf(var[c] + BN_EPS) * gamma[c];
        sc[j] = s;
        sh[j] = beta[c] - mean[c] * s;
    }
#pragma unroll
    for (int i = 0; i < 4; ++i) {
#pragma unroll
        for (int reg = 0; reg < 4; ++reg) {
            const int row = row0 + wr * 64 + i * 16 + quad * 4 + reg;
            if (row >= N) continue;
            float xq[10];
            const float* xp = &x[(size_t)row * IN_FEAT + p * 10];
#pragma unroll
            for (int q = 0; q < 10; ++q) xq[q] = xp[q];
#pragma unroll
            for (int j = 0; j < 4; ++j) {
                const int c = j * 16 + l15;
                float v = acc[i][j][reg];
#pragma unroll
                for (int q = 0; q < 10; ++q) v = fmaf(xq[q], lw[c * 10 + q], v);
                v = fmaxf(v * sc[j] + sh[j], 0.0f);
                out[((size_t)row * 32 + p) * 128 + c] = v;
            }
        }
    }
}

// Max over the 32 points per (n, c), broadcast into out[n][p][64+c].
__global__ __launch_bounds__(256) void pfn_maxcat(float* __restrict__ out, int N) {
    const int n = blockIdx.x;
    const int c = threadIdx.x & 63;
    const int g = threadIdx.x >> 6;
    __shared__ float red[4][64];
    float m = 0.0f;
    for (int pp = g; pp < 32; pp += 4)
        m = fmaxf(m, out[((size_t)n * 32 + pp) * 128 + c]);
    red[g][c] = m;
    __syncthreads();
    m = fmaxf(fmaxf(red[0][c], red[1][c]), fmaxf(red[2][c], red[3][c]));
    for (int pp = g; pp < 32; pp += 4)
        out[((size_t)n * 32 + pp) * 128 + 64 + c] = m;
}

extern "C" void kernel_launch(void* const* d_in, const int* in_sizes, int n_in,
                              void* d_out, int out_size, void* d_ws, size_t ws_size,
                              hipStream_t stream) {
    const float* x     = (const float*)d_in[0];
    const float* lw    = (const float*)d_in[1];
    const float* bw    = (const float*)d_in[2];
    const float* sw    = (const float*)d_in[3];
    const float* ss    = (const float*)d_in[4];
    const float* gamma = (const float*)d_in[5];
    const float* beta  = (const float*)d_in[6];
    const float* mean  = (const float*)d_in[7];
    const float* var   = (const float*)d_in[8];
    float* out = (float*)d_out;

    const int N = in_sizes[0] / IN_FEAT;
    const int nbx = (N + BM - 1) / BM;
    const size_t w_bytes = (size_t)OUT_FEAT * KTOT * sizeof(bf16);
    const size_t a_bytes = (size_t)nbx * BM * KTOT * sizeof(bf16);

    if (ws_size >= A_OFF + a_bytes) {
        bf16* W = (bf16*)d_ws;
        bf16* A = (bf16*)((char*)d_ws + A_OFF);
        prep_w<<<dim3((KTOT + 255) / 256, OUT_FEAT), 256, 0, stream>>>(bw, sw, ss, W);
        prep_a<<<(N * IN_FEAT + 255) / 256, 256, 0, stream>>>(x, A, N * IN_FEAT);
        const int supers = (nbx + 31) / 32;
        pfn_gemm_ws<<<supers * 512, 256, 0, stream>>>(x, A, W, lw, gamma, beta,
                                                      mean, var, out, N, nbx);
    } else if (ws_size >= w_bytes) {
        bf16* W = (bf16*)d_ws;
        prep_w<<<dim3((KTOT + 255) / 256, OUT_FEAT), 256, 0, stream>>>(bw, sw, ss, W);
        pfn_gemm<true><<<dim3(nbx, OUT_FEAT / BN), 256, 0, stream>>>(
            x, W, bw, sw, ss, lw, gamma, beta, mean, var, out, N);
    } else {
        pfn_gemm<false><<<dim3(nbx, OUT_FEAT / BN), 256, 0, stream>>>(
            x, nullptr, bw, sw, ss, lw, gamma, beta, mean, var, out, N);
    }
    pfn_maxcat<<<N, 256, 0, stream>>>(out, N);
}

// Round 4
// 1581.964 us; speedup vs baseline: 1.0819x; 1.0819x over previous
//
#include <hip/hip_runtime.h>
#include <cstdint>
#include <math.h>

#define IN_FEAT 320
#define OUT_FEAT 2048
#define NB 8
#define KSIL 320
#define KTOT 2880          // 320 silu + 2560 spline-basis columns
#define BM1 256            // tier-1 M tile
#define BN1 128            // tier-1 N tile
#define BM 128             // tier-2 fallback tiles
#define BN 128
#define BK 32
#define LDA 40             // tier-2 fallback LDS stride
#define BN_EPS 1e-3f
#define A_OFF ((size_t)16 << 20)   // A starts 16 MB into d_ws (W lives below)

typedef __bf16 bf16;
typedef __attribute__((ext_vector_type(8))) __bf16 bf16x8;
typedef __attribute__((ext_vector_type(4))) float f32x4;

// Uniform cubic B-spline closed form == reference Cox-de Boor recursion.
__device__ __forceinline__ void bspline8(float xv, float* b) {
    float xc = (xv + 2.2f) * 2.5f;
    float cf = floorf(xc);
    int c = (int)cf;
    float t = xc - cf;
    float omt = 1.0f - t;
    float t2 = t * t, t3 = t2 * t;
    float w0 = omt * omt * omt * (1.0f / 6.0f);
    float w1 = (3.0f * t3 - 6.0f * t2 + 4.0f) * (1.0f / 6.0f);
    float w2 = (-3.0f * t3 + 3.0f * t2 + 3.0f * t + 1.0f) * (1.0f / 6.0f);
    float w3 = t3 * (1.0f / 6.0f);
    if (xc < 0.0f) { w0 = w1 = w2 = w3 = 0.0f; }
#pragma unroll
    for (int j = 0; j < 8; ++j) {
        int d = c - j;
        b[j] = (d == 3) ? w0 : (d == 2) ? w1 : (d == 1) ? w2 : (d == 0) ? w3 : 0.0f;
    }
}

__device__ __forceinline__ bf16x8 pack8(const float* f) {
    bf16x8 v;
#pragma unroll
    for (int j = 0; j < 8; ++j) v[j] = (bf16)f[j];
    return v;
}

__device__ __forceinline__ void gl2lds16(const bf16* g, bf16* l) {
    __builtin_amdgcn_global_load_lds(
        (const __attribute__((address_space(1))) void*)g,
        (__attribute__((address_space(3))) void*)l, 16, 0, 0);
}

// Fuse W = [base_weight | spline_weight*scaler] -> bf16, k-major W[o][2880].
// Vectorized: each thread produces 8 consecutive k (16-B store).
__global__ __launch_bounds__(256) void prep_w(const float* __restrict__ bw,
                                              const float* __restrict__ sw,
                                              const float* __restrict__ ss,
                                              bf16* __restrict__ W) {
    const int t = blockIdx.x * 256 + threadIdx.x;   // [0, OUT_FEAT*360)
    if (t >= OUT_FEAT * (KTOT / 8)) return;
    const int o = t / (KTOT / 8);
    const int m = t - o * (KTOT / 8);
    const int k0 = m * 8;
    float w[8];
    if (k0 < KSIL) {
        const float* p = &bw[o * IN_FEAT + k0];
#pragma unroll
        for (int u = 0; u < 8; ++u) w[u] = p[u];
    } else {
        const int i = (k0 - KSIL) >> 3;
        const float s = ss[o * IN_FEAT + i];
        const float* p = &sw[(o * IN_FEAT + i) * NB];
#pragma unroll
        for (int u = 0; u < 8; ++u) w[u] = p[u] * s;
    }
    *(bf16x8*)&W[(size_t)o * KTOT + k0] = pack8(w);
}

// Precompute A = [silu(x) | bases(x)] bf16, k-major A[row][2880].
// Vectorized: each thread handles 8 consecutive input features of one row
// (32-B read, 16-B silu store, 128-B contiguous spline store).
__global__ __launch_bounds__(256) void prep_a(const float* __restrict__ x,
                                              bf16* __restrict__ A, int total8) {
    const int t = blockIdx.x * 256 + threadIdx.x;   // [0, N*40)
    if (t >= total8) return;
    const int row = t / (IN_FEAT / 8);
    const int f0 = (t - row * (IN_FEAT / 8)) * 8;
    const float4 v0 = *(const float4*)&x[(size_t)row * IN_FEAT + f0];
    const float4 v1 = *(const float4*)&x[(size_t)row * IN_FEAT + f0 + 4];
    float xv[8] = {v0.x, v0.y, v0.z, v0.w, v1.x, v1.y, v1.z, v1.w};
    float sil[8];
#pragma unroll
    for (int u = 0; u < 8; ++u) sil[u] = xv[u] / (1.0f + __expf(-xv[u]));
    bf16* ar = A + (size_t)row * KTOT;
    *(bf16x8*)&ar[f0] = pack8(sil);
#pragma unroll
    for (int u = 0; u < 8; ++u) {
        float b[8];
        bspline8(xv[u], b);
        *(bf16x8*)&ar[KSIL + (f0 + u) * 8] = pack8(b);
    }
}

// Tier-1: pure GEMM from precomputed A (ws) and W (ws), 256x128 tile,
// 8 waves (4 M x 2 N, 64x64 each), global_load_lds staging with XOR-swizzled
// LDS, plain __syncthreads discipline (measured best), fused epilogue.
__global__ __launch_bounds__(512)
void pfn_gemm_ws(const float* __restrict__ x, const bf16* __restrict__ A,
                 const bf16* __restrict__ W, const float* __restrict__ lw,
                 const float* __restrict__ gamma, const float* __restrict__ beta,
                 const float* __restrict__ mean, const float* __restrict__ var,
                 float* __restrict__ out, int N, int nbx) {
    __shared__ bf16 As[BM1 * BK];   // 16 KB
    __shared__ bf16 Bs[BN1 * BK];   // 8 KB

    // super-tile remap: 32 bx-tiles x 16 by-tiles per group.
    // blk and blk+32 share bx's A-panel and land on the same XCD (32%8==0).
    const int blk = blockIdx.x;
    const int sid = blk >> 9;
    const int t = blk & 511;
    const int by = t >> 5;
    const int bx = (sid << 5) + (t & 31);
    if (bx >= nbx) return;

    const int row0 = bx * BM1;
    const int col0 = by * BN1;
    const int tid = threadIdx.x;
    const int wave = tid >> 6;
    const int lane = tid & 63;
    const int wr = wave >> 1;        // 0..3 -> 64-row slice
    const int wc = wave & 1;         // 0..1 -> 64-col slice
    const int l15 = lane & 15;
    const int quad = lane >> 4;

    // staging: chunk q -> LDS byte q*16, row r=q>>2, k-group g=(q&3)^((r>>1)&3)
    const int r0 = tid >> 2;         // 0..127
    const int s0 = tid & 3;
    const int g0 = s0 ^ ((r0 >> 1) & 3);
    const bf16* a0 = A + (size_t)(row0 + r0) * KTOT + g0 * 8;
    const bf16* a1 = a0 + (size_t)128 * KTOT;            // rows 128..255
    const bf16* b0 = W + (size_t)(col0 + r0) * KTOT + g0 * 8;
    bf16* lA0 = As + tid * 8;
    bf16* lA1 = As + (tid + 512) * 8;
    bf16* lB0 = Bs + tid * 8;

    // fragment-read swizzle slot (row low bits == l15 low bits)
    const int sfr = quad ^ ((l15 >> 1) & 3);

    f32x4 acc[4][4] = {};

    for (int kc = 0; kc < KTOT; kc += BK) {
        __syncthreads();
        gl2lds16(a0 + kc, lA0);
        gl2lds16(a1 + kc, lA1);
        gl2lds16(b0 + kc, lB0);
        __syncthreads();
        bf16x8 af[4], bv[4];
#pragma unroll
        for (int i = 0; i < 4; ++i)
            af[i] = *(const bf16x8*)&As[(wr * 64 + i * 16 + l15) * BK + sfr * 8];
#pragma unroll
        for (int j = 0; j < 4; ++j)
            bv[j] = *(const bf16x8*)&Bs[(wc * 64 + j * 16 + l15) * BK + sfr * 8];
#pragma unroll
        for (int i = 0; i < 4; ++i)
#pragma unroll
            for (int j = 0; j < 4; ++j)
                acc[i][j] = __builtin_amdgcn_mfma_f32_16x16x32_bf16(af[i], bv[j],
                                                                   acc[i][j], 0, 0, 0);
    }

    // epilogue: + linear path, BN, ReLU, store
    const int p = by * 2 + wc;
    float sc[4], sh[4];
#pragma unroll
    for (int j = 0; j < 4; ++j) {
        const int c = j * 16 + l15;
        const float s = rsqrtf(var[c] + BN_EPS) * gamma[c];
        sc[j] = s;
        sh[j] = beta[c] - mean[c] * s;
    }
#pragma unroll
    for (int i = 0; i < 4; ++i) {
#pragma unroll
        for (int reg = 0; reg < 4; ++reg) {
            const int row = row0 + wr * 64 + i * 16 + quad * 4 + reg;
            if (row >= N) continue;
            float xq[10];
            const float* xp = &x[(size_t)row * IN_FEAT + p * 10];
#pragma unroll
            for (int q = 0; q < 10; ++q) xq[q] = xp[q];
#pragma unroll
            for (int j = 0; j < 4; ++j) {
                const int c = j * 16 + l15;
                float v = acc[i][j][reg];
#pragma unroll
                for (int q = 0; q < 10; ++q) v = fmaf(xq[q], lw[c * 10 + q], v);
                v = fmaxf(v * sc[j] + sh[j], 0.0f);
                out[((size_t)row * 32 + p) * 128 + c] = v;
            }
        }
    }
}

// ---- Tier-2/0 fallback: round-2 fused kernel (known-correct) ----
template <bool HASW>
__global__ __launch_bounds__(256)
void pfn_gemm(const float* __restrict__ x, const bf16* __restrict__ W,
              const float* __restrict__ bw, const float* __restrict__ sw,
              const float* __restrict__ ss, const float* __restrict__ lw,
              const float* __restrict__ gamma, const float* __restrict__ beta,
              const float* __restrict__ mean, const float* __restrict__ var,
              float* __restrict__ out, int N) {
    __shared__ bf16 As[BM * LDA];
    __shared__ bf16 Bs[BN * LDA];
    const int tid = threadIdx.x;
    const int row0 = blockIdx.x * BM;
    const int col0 = blockIdx.y * BN;
    const int wave = tid >> 6;
    const int lane = tid & 63;
    const int wr = wave >> 1;
    const int wc = wave & 1;
    const int l15 = lane & 15;
    const int quad = lane >> 4;
    f32x4 acc[4][4] = {};
    auto stage_b = [&](int kc) {
        const int ol = tid >> 1;
        const int k0 = (tid & 1) * 16;
        if (HASW) {
            const bf16x8* src = (const bf16x8*)&W[(size_t)(col0 + ol) * KTOT + kc + k0];
            *(bf16x8*)&Bs[ol * LDA + k0] = src[0];
            *(bf16x8*)&Bs[ol * LDA + k0 + 8] = src[1];
        } else {
            const int o = col0 + ol;
#pragma unroll
            for (int u = 0; u < 16; ++u) {
                const int gk = kc + k0 + u;
                float w;
                if (gk < KSIL) {
                    w = bw[o * IN_FEAT + gk];
                } else {
                    const int s = gk - KSIL;
                    const int i = s >> 3, j = s & 7;
                    w = sw[(o * IN_FEAT + i) * NB + j] * ss[o * IN_FEAT + i];
                }
                Bs[ol * LDA + k0 + u] = (bf16)w;
            }
        }
    };
    auto mma_step = [&]() {
        bf16x8 af[4], bv[4];
#pragma unroll
        for (int i = 0; i < 4; ++i)
            af[i] = *(const bf16x8*)&As[(wr * 64 + i * 16 + l15) * LDA + quad * 8];
#pragma unroll
        for (int j = 0; j < 4; ++j)
            bv[j] = *(const bf16x8*)&Bs[(wc * 64 + j * 16 + l15) * LDA + quad * 8];
#pragma unroll
        for (int i = 0; i < 4; ++i)
#pragma unroll
            for (int j = 0; j < 4; ++j)
                acc[i][j] = __builtin_amdgcn_mfma_f32_16x16x32_bf16(af[i], bv[j],
                                                                   acc[i][j], 0, 0, 0);
    };
    for (int kc = 0; kc < KSIL; kc += BK) {
        __syncthreads();
        stage_b(kc);
        {
            const int r = tid >> 1;
            const int k0 = (tid & 1) * 16;
            const int row = row0 + r;
            float v[16];
            if (row < N) {
                const float* xp = &x[(size_t)row * IN_FEAT + kc + k0];
#pragma unroll
                for (int u = 0; u < 16; ++u) {
                    const float xv = xp[u];
                    v[u] = xv / (1.0f + __expf(-xv));
                }
            } else {
#pragma unroll
                for (int u = 0; u < 16; ++u) v[u] = 0.0f;
            }
            *(bf16x8*)&As[r * LDA + k0] = pack8(v);
            *(bf16x8*)&As[r * LDA + k0 + 8] = pack8(v + 8);
        }
        __syncthreads();
        mma_step();
    }
    for (int kc = KSIL; kc < KTOT; kc += BK) {
        __syncthreads();
        stage_b(kc);
        {
            const int i0 = (kc - KSIL) >> 3;
#pragma unroll
            for (int s = 0; s < 2; ++s) {
                const int task = tid + s * 256;
                const int r = task >> 2;
                const int f = task & 3;
                const int row = row0 + r;
                float b[8];
                if (row < N) {
                    bspline8(x[(size_t)row * IN_FEAT + i0 + f], b);
                } else {
#pragma unroll
                    for (int j = 0; j < 8; ++j) b[j] = 0.0f;
                }
                *(bf16x8*)&As[r * LDA + f * 8] = pack8(b);
            }
        }
        __syncthreads();
        mma_step();
    }
    const int p = blockIdx.y * 2 + wc;
    float sc[4], sh[4];
#pragma unroll
    for (int j = 0; j < 4; ++j) {
        const int c = j * 16 + l15;
        const float s = rsqrtf(var[c] + BN_EPS) * gamma[c];
        sc[j] = s;
        sh[j] = beta[c] - mean[c] * s;
    }
#pragma unroll
    for (int i = 0; i < 4; ++i) {
#pragma unroll
        for (int reg = 0; reg < 4; ++reg) {
            const int row = row0 + wr * 64 + i * 16 + quad * 4 + reg;
            if (row >= N) continue;
            float xq[10];
            const float* xp = &x[(size_t)row * IN_FEAT + p * 10];
#pragma unroll
            for (int q = 0; q < 10; ++q) xq[q] = xp[q];
#pragma unroll
            for (int j = 0; j < 4; ++j) {
                const int c = j * 16 + l15;
                float v = acc[i][j][reg];
#pragma unroll
                for (int q = 0; q < 10; ++q) v = fmaf(xq[q], lw[c * 10 + q], v);
                v = fmaxf(v * sc[j] + sh[j], 0.0f);
                out[((size_t)row * 32 + p) * 128 + c] = v;
            }
        }
    }
}

// Max over the 32 points per (n, c), broadcast into out[n][p][64+c].
// Vectorized float4: 16 lanes cover c=0..63; 16 samples per block.
__global__ __launch_bounds__(256) void pfn_maxcat(float* __restrict__ out, int N) {
    const int n = blockIdx.x * 16 + (threadIdx.x >> 4);
    const int q = threadIdx.x & 15;
    if (n >= N) return;
    float* base = out + (size_t)n * 32 * 128 + q * 4;
    f32x4 m = {0.0f, 0.0f, 0.0f, 0.0f};   // post-ReLU values are >= 0
#pragma unroll
    for (int pp = 0; pp < 32; ++pp) {
        const f32x4 v = *(const f32x4*)&base[pp * 128];
        m[0] = fmaxf(m[0], v[0]);
        m[1] = fmaxf(m[1], v[1]);
        m[2] = fmaxf(m[2], v[2]);
        m[3] = fmaxf(m[3], v[3]);
    }
#pragma unroll
    for (int pp = 0; pp < 32; ++pp)
        *(f32x4*)&base[pp * 128 + 64] = m;
}

extern "C" void kernel_launch(void* const* d_in, const int* in_sizes, int n_in,
                              void* d_out, int out_size, void* d_ws, size_t ws_size,
                              hipStream_t stream) {
    const float* x     = (const float*)d_in[0];
    const float* lw    = (const float*)d_in[1];
    const float* bw    = (const float*)d_in[2];
    const float* sw    = (const float*)d_in[3];
    const float* ss    = (const float*)d_in[4];
    const float* gamma = (const float*)d_in[5];
    const float* beta  = (const float*)d_in[6];
    const float* mean  = (const float*)d_in[7];
    const float* var   = (const float*)d_in[8];
    float* out = (float*)d_out;

    const int N = in_sizes[0] / IN_FEAT;
    const int nbx = (N + BM1 - 1) / BM1;
    const size_t w_bytes = (size_t)OUT_FEAT * KTOT * sizeof(bf16);
    const size_t a_bytes = (size_t)nbx * BM1 * KTOT * sizeof(bf16);

    if (ws_size >= A_OFF + a_bytes) {
        bf16* W = (bf16*)d_ws;
        bf16* A = (bf16*)((char*)d_ws + A_OFF);
        prep_w<<<(OUT_FEAT * (KTOT / 8) + 255) / 256, 256, 0, stream>>>(bw, sw, ss, W);
        const int total8 = N * (IN_FEAT / 8);
        prep_a<<<(total8 + 255) / 256, 256, 0, stream>>>(x, A, total8);
        const int supers = (nbx + 31) / 32;
        pfn_gemm_ws<<<supers * 512, 512, 0, stream>>>(x, A, W, lw, gamma, beta,
                                                      mean, var, out, N, nbx);
    } else if (ws_size >= w_bytes) {
        bf16* W = (bf16*)d_ws;
        prep_w<<<(OUT_FEAT * (KTOT / 8) + 255) / 256, 256, 0, stream>>>(bw, sw, ss, W);
        pfn_gemm<true><<<dim3((N + BM - 1) / BM, OUT_FEAT / BN), 256, 0, stream>>>(
            x, W, bw, sw, ss, lw, gamma, beta, mean, var, out, N);
    } else {
        pfn_gemm<false><<<dim3((N + BM - 1) / BM, OUT_FEAT / BN), 256, 0, stream>>>(
            x, nullptr, bw, sw, ss, lw, gamma, beta, mean, var, out, N);
    }
    pfn_maxcat<<<(N + 15) / 16, 256, 0, stream>>>(out, N);
}

// Round 6
// 1503.554 us; speedup vs baseline: 1.1383x; 1.0521x over previous
//
#include <hip/hip_runtime.h>
#include <cstdint>
#include <math.h>

#define IN_FEAT 320
#define OUT_FEAT 2048
#define NB 8
#define KSIL 320
#define KTOT 2880          // 320 silu + 2560 spline-basis columns
#define BM1 256            // tier-1 M tile
#define BN1 256            // tier-1 N tile
#define BK1 64             // tier-1 K step (two MFMA k-halves)
#define NT1 (KTOT / BK1)   // 45 steps
#define BM 128             // tier-2 fallback tiles
#define BN 128
#define BK 32
#define LDA 40             // tier-2 fallback LDS stride
#define BN_EPS 1e-3f
#define A_OFF ((size_t)16 << 20)   // A starts 16 MB into d_ws (W lives below)

typedef __bf16 bf16;
typedef __attribute__((ext_vector_type(8))) __bf16 bf16x8;
typedef __attribute__((ext_vector_type(4))) float f32x4;

// Uniform cubic B-spline closed form == reference Cox-de Boor recursion.
__device__ __forceinline__ void bspline8(float xv, float* b) {
    float xc = (xv + 2.2f) * 2.5f;
    float cf = floorf(xc);
    int c = (int)cf;
    float t = xc - cf;
    float omt = 1.0f - t;
    float t2 = t * t, t3 = t2 * t;
    float w0 = omt * omt * omt * (1.0f / 6.0f);
    float w1 = (3.0f * t3 - 6.0f * t2 + 4.0f) * (1.0f / 6.0f);
    float w2 = (-3.0f * t3 + 3.0f * t2 + 3.0f * t + 1.0f) * (1.0f / 6.0f);
    float w3 = t3 * (1.0f / 6.0f);
    if (xc < 0.0f) { w0 = w1 = w2 = w3 = 0.0f; }
#pragma unroll
    for (int j = 0; j < 8; ++j) {
        int d = c - j;
        b[j] = (d == 3) ? w0 : (d == 2) ? w1 : (d == 1) ? w2 : (d == 0) ? w3 : 0.0f;
    }
}

__device__ __forceinline__ bf16x8 pack8(const float* f) {
    bf16x8 v;
#pragma unroll
    for (int j = 0; j < 8; ++j) v[j] = (bf16)f[j];
    return v;
}

__device__ __forceinline__ void gl2lds16(const bf16* g, bf16* l) {
    __builtin_amdgcn_global_load_lds(
        (const __attribute__((address_space(1))) void*)g,
        (__attribute__((address_space(3))) void*)l, 16, 0, 0);
}

// Fuse W = [base_weight | spline_weight*scaler] -> bf16, k-major W[o][2880].
// Vectorized: each thread produces 8 consecutive k (16-B store).
__global__ __launch_bounds__(256) void prep_w(const float* __restrict__ bw,
                                              const float* __restrict__ sw,
                                              const float* __restrict__ ss,
                                              bf16* __restrict__ W) {
    const int t = blockIdx.x * 256 + threadIdx.x;   // [0, OUT_FEAT*360)
    if (t >= OUT_FEAT * (KTOT / 8)) return;
    const int o = t / (KTOT / 8);
    const int m = t - o * (KTOT / 8);
    const int k0 = m * 8;
    float w[8];
    if (k0 < KSIL) {
        const float* p = &bw[o * IN_FEAT + k0];
#pragma unroll
        for (int u = 0; u < 8; ++u) w[u] = p[u];
    } else {
        const int i = (k0 - KSIL) >> 3;
        const float s = ss[o * IN_FEAT + i];
        const float* p = &sw[(o * IN_FEAT + i) * NB];
#pragma unroll
        for (int u = 0; u < 8; ++u) w[u] = p[u] * s;
    }
    *(bf16x8*)&W[(size_t)o * KTOT + k0] = pack8(w);
}

// Precompute A = [silu(x) | bases(x)] bf16, k-major A[row][2880].
// Vectorized: each thread handles 8 consecutive input features of one row
// (32-B read, 16-B silu store, 128-B contiguous spline store).
__global__ __launch_bounds__(256) void prep_a(const float* __restrict__ x,
                                              bf16* __restrict__ A, int total8) {
    const int t = blockIdx.x * 256 + threadIdx.x;   // [0, N*40)
    if (t >= total8) return;
    const int row = t / (IN_FEAT / 8);
    const int f0 = (t - row * (IN_FEAT / 8)) * 8;
    const float4 v0 = *(const float4*)&x[(size_t)row * IN_FEAT + f0];
    const float4 v1 = *(const float4*)&x[(size_t)row * IN_FEAT + f0 + 4];
    float xv[8] = {v0.x, v0.y, v0.z, v0.w, v1.x, v1.y, v1.z, v1.w};
    float sil[8];
#pragma unroll
    for (int u = 0; u < 8; ++u) sil[u] = xv[u] / (1.0f + __expf(-xv[u]));
    bf16* ar = A + (size_t)row * KTOT;
    *(bf16x8*)&ar[f0] = pack8(sil);
#pragma unroll
    for (int u = 0; u < 8; ++u) {
        float b[8];
        bspline8(xv[u], b);
        *(bf16x8*)&ar[KSIL + (f0 + u) * 8] = pack8(b);
    }
}

// Tier-1: pure GEMM from precomputed A (ws) and W (ws).
// 256x256 tile, BK=64, 16 waves (4Mx4N, 64x64 each), 1024 threads.
// Double-buffered LDS (2x64 KB): stage tile t+1 before computing tile t,
// one __syncthreads (vmcnt drain) per step. XOR-swizzled LDS (8 slots/row),
// fused linear-path/BN/ReLU epilogue.
__global__ __launch_bounds__(1024)
void pfn_gemm_ws(const float* __restrict__ x, const bf16* __restrict__ A,
                 const bf16* __restrict__ W, const float* __restrict__ lw,
                 const float* __restrict__ gamma, const float* __restrict__ beta,
                 const float* __restrict__ mean, const float* __restrict__ var,
                 float* __restrict__ out, int N, int nbx) {
    __shared__ bf16 As[2][BM1 * BK1];   // 2 x 32 KB
    __shared__ bf16 Bs[2][BN1 * BK1];   // 2 x 32 KB  (128 KB total)

    // super-tile remap: 32 bx-tiles x 8 by-tiles per group (A slab L3-hot).
    const int blk = blockIdx.x;
    const int sid = blk >> 8;
    const int t = blk & 255;
    const int by = t >> 5;              // 0..7
    const int bx = (sid << 5) + (t & 31);
    if (bx >= nbx) return;

    const int row0 = bx * BM1;
    const int col0 = by * BN1;
    const int tid = threadIdx.x;
    const int wave = tid >> 6;
    const int lane = tid & 63;
    const int wr = wave >> 2;           // 0..3 -> 64-row slice
    const int wc = wave & 3;            // 0..3 -> 64-col slice
    const int l15 = lane & 15;
    const int quad = lane >> 4;

    // staging: thread owns 16-B chunks tid and tid+1024 of each tile.
    // chunk q -> LDS byte q*16 = row r=q>>3, slot s=q&7; slot s of row r
    // holds global k-group g = s ^ (r&7)  (XOR swizzle, 8x16B slots/row).
    const int r0 = tid >> 3;            // 0..127
    const int s0 = tid & 7;
    const int g0 = s0 ^ (r0 & 7);
    const bf16* a0 = A + (size_t)(row0 + r0) * KTOT + g0 * 8;
    const bf16* a1 = a0 + (size_t)128 * KTOT;            // rows 128..255
    const bf16* b0 = W + (size_t)(col0 + r0) * KTOT + g0 * 8;
    const bf16* b1 = b0 + (size_t)128 * KTOT;

    // fragment-read: k-group kg = 4*half + quad lives in slot kg ^ (row&7);
    // fragment rows vary only in l15 (wr*64, i*16 are 0 mod 8).
    const int h7 = l15 & 7;

    f32x4 acc[4][4] = {};

    auto stage = [&](int b, int kc) {
        gl2lds16(a0 + kc, &As[b][tid * 8]);
        gl2lds16(a1 + kc, &As[b][(tid + 1024) * 8]);
        gl2lds16(b0 + kc, &Bs[b][tid * 8]);
        gl2lds16(b1 + kc, &Bs[b][(tid + 1024) * 8]);
    };
    auto compute = [&](int b) {
#pragma unroll
        for (int half = 0; half < 2; ++half) {
            const int sfr = ((half << 2) | quad) ^ h7;
            bf16x8 af[4], bv[4];
#pragma unroll
            for (int i = 0; i < 4; ++i)
                af[i] = *(const bf16x8*)&As[b][(wr * 64 + i * 16 + l15) * BK1 + sfr * 8];
#pragma unroll
            for (int j = 0; j < 4; ++j)
                bv[j] = *(const bf16x8*)&Bs[b][(wc * 64 + j * 16 + l15) * BK1 + sfr * 8];
#pragma unroll
            for (int i = 0; i < 4; ++i)
#pragma unroll
                for (int j = 0; j < 4; ++j)
                    acc[i][j] = __builtin_amdgcn_mfma_f32_16x16x32_bf16(
                        af[i], bv[j], acc[i][j], 0, 0, 0);
        }
    };

    stage(0, 0);
    __syncthreads();                    // drain prologue stage
    int cur = 0;
    for (int tt = 0; tt < NT1; ++tt) {
        if (tt + 1 < NT1) stage(cur ^ 1, (tt + 1) * BK1);
        compute(cur);
        __syncthreads();                // drains this step's stage (vmcnt 0)
        cur ^= 1;
    }

    // epilogue: + linear path, BN, ReLU, store
    const int p = by * 4 + wc;
    float sc[4], sh[4];
#pragma unroll
    for (int j = 0; j < 4; ++j) {
        const int c = j * 16 + l15;
        const float s = rsqrtf(var[c] + BN_EPS) * gamma[c];
        sc[j] = s;
        sh[j] = beta[c] - mean[c] * s;
    }
#pragma unroll
    for (int i = 0; i < 4; ++i) {
#pragma unroll
        for (int reg = 0; reg < 4; ++reg) {
            const int row = row0 + wr * 64 + i * 16 + quad * 4 + reg;
            if (row >= N) continue;
            float xq[10];
            const float* xp = &x[(size_t)row * IN_FEAT + p * 10];
#pragma unroll
            for (int q = 0; q < 10; ++q) xq[q] = xp[q];
#pragma unroll
            for (int j = 0; j < 4; ++j) {
                const int c = j * 16 + l15;
                float v = acc[i][j][reg];
#pragma unroll
                for (int q = 0; q < 10; ++q) v = fmaf(xq[q], lw[c * 10 + q], v);
                v = fmaxf(v * sc[j] + sh[j], 0.0f);
                out[((size_t)row * 32 + p) * 128 + c] = v;
            }
        }
    }
}

// ---- Tier-2/0 fallback: round-2 fused kernel (known-correct) ----
template <bool HASW>
__global__ __launch_bounds__(256)
void pfn_gemm(const float* __restrict__ x, const bf16* __restrict__ W,
              const float* __restrict__ bw, const float* __restrict__ sw,
              const float* __restrict__ ss, const float* __restrict__ lw,
              const float* __restrict__ gamma, const float* __restrict__ beta,
              const float* __restrict__ mean, const float* __restrict__ var,
              float* __restrict__ out, int N) {
    __shared__ bf16 As[BM * LDA];
    __shared__ bf16 Bs[BN * LDA];
    const int tid = threadIdx.x;
    const int row0 = blockIdx.x * BM;
    const int col0 = blockIdx.y * BN;
    const int wave = tid >> 6;
    const int lane = tid & 63;
    const int wr = wave >> 1;
    const int wc = wave & 1;
    const int l15 = lane & 15;
    const int quad = lane >> 4;
    f32x4 acc[4][4] = {};
    auto stage_b = [&](int kc) {
        const int ol = tid >> 1;
        const int k0 = (tid & 1) * 16;
        if (HASW) {
            const bf16x8* src = (const bf16x8*)&W[(size_t)(col0 + ol) * KTOT + kc + k0];
            *(bf16x8*)&Bs[ol * LDA + k0] = src[0];
            *(bf16x8*)&Bs[ol * LDA + k0 + 8] = src[1];
        } else {
            const int o = col0 + ol;
#pragma unroll
            for (int u = 0; u < 16; ++u) {
                const int gk = kc + k0 + u;
                float w;
                if (gk < KSIL) {
                    w = bw[o * IN_FEAT + gk];
                } else {
                    const int s = gk - KSIL;
                    const int i = s >> 3, j = s & 7;
                    w = sw[(o * IN_FEAT + i) * NB + j] * ss[o * IN_FEAT + i];
                }
                Bs[ol * LDA + k0 + u] = (bf16)w;
            }
        }
    };
    auto mma_step = [&]() {
        bf16x8 af[4], bv[4];
#pragma unroll
        for (int i = 0; i < 4; ++i)
            af[i] = *(const bf16x8*)&As[(wr * 64 + i * 16 + l15) * LDA + quad * 8];
#pragma unroll
        for (int j = 0; j < 4; ++j)
            bv[j] = *(const bf16x8*)&Bs[(wc * 64 + j * 16 + l15) * LDA + quad * 8];
#pragma unroll
        for (int i = 0; i < 4; ++i)
#pragma unroll
            for (int j = 0; j < 4; ++j)
                acc[i][j] = __builtin_amdgcn_mfma_f32_16x16x32_bf16(af[i], bv[j],
                                                                   acc[i][j], 0, 0, 0);
    };
    for (int kc = 0; kc < KSIL; kc += BK) {
        __syncthreads();
        stage_b(kc);
        {
            const int r = tid >> 1;
            const int k0 = (tid & 1) * 16;
            const int row = row0 + r;
            float v[16];
            if (row < N) {
                const float* xp = &x[(size_t)row * IN_FEAT + kc + k0];
#pragma unroll
                for (int u = 0; u < 16; ++u) {
                    const float xv = xp[u];
                    v[u] = xv / (1.0f + __expf(-xv));
                }
            } else {
#pragma unroll
                for (int u = 0; u < 16; ++u) v[u] = 0.0f;
            }
            *(bf16x8*)&As[r * LDA + k0] = pack8(v);
            *(bf16x8*)&As[r * LDA + k0 + 8] = pack8(v + 8);
        }
        __syncthreads();
        mma_step();
    }
    for (int kc = KSIL; kc < KTOT; kc += BK) {
        __syncthreads();
        stage_b(kc);
        {
            const int i0 = (kc - KSIL) >> 3;
#pragma unroll
            for (int s = 0; s < 2; ++s) {
                const int task = tid + s * 256;
                const int r = task >> 2;
                const int f = task & 3;
                const int row = row0 + r;
                float b[8];
                if (row < N) {
                    bspline8(x[(size_t)row * IN_FEAT + i0 + f], b);
                } else {
#pragma unroll
                    for (int j = 0; j < 8; ++j) b[j] = 0.0f;
                }
                *(bf16x8*)&As[r * LDA + f * 8] = pack8(b);
            }
        }
        __syncthreads();
        mma_step();
    }
    const int p = blockIdx.y * 2 + wc;
    float sc[4], sh[4];
#pragma unroll
    for (int j = 0; j < 4; ++j) {
        const int c = j * 16 + l15;
        const float s = rsqrtf(var[c] + BN_EPS) * gamma[c];
        sc[j] = s;
        sh[j] = beta[c] - mean[c] * s;
    }
#pragma unroll
    for (int i = 0; i < 4; ++i) {
#pragma unroll
        for (int reg = 0; reg < 4; ++reg) {
            const int row = row0 + wr * 64 + i * 16 + quad * 4 + reg;
            if (row >= N) continue;
            float xq[10];
            const float* xp = &x[(size_t)row * IN_FEAT + p * 10];
#pragma unroll
            for (int q = 0; q < 10; ++q) xq[q] = xp[q];
#pragma unroll
            for (int j = 0; j < 4; ++j) {
                const int c = j * 16 + l15;
                float v = acc[i][j][reg];
#pragma unroll
                for (int q = 0; q < 10; ++q) v = fmaf(xq[q], lw[c * 10 + q], v);
                v = fmaxf(v * sc[j] + sh[j], 0.0f);
                out[((size_t)row * 32 + p) * 128 + c] = v;
            }
        }
    }
}

// Max over the 32 points per (n, c), broadcast into out[n][p][64+c].
// Vectorized float4: 16 lanes cover c=0..63; 16 samples per block.
__global__ __launch_bounds__(256) void pfn_maxcat(float* __restrict__ out, int N) {
    const int n = blockIdx.x * 16 + (threadIdx.x >> 4);
    const int q = threadIdx.x & 15;
    if (n >= N) return;
    float* base = out + (size_t)n * 32 * 128 + q * 4;
    f32x4 m = {0.0f, 0.0f, 0.0f, 0.0f};   // post-ReLU values are >= 0
#pragma unroll
    for (int pp = 0; pp < 32; ++pp) {
        const f32x4 v = *(const f32x4*)&base[pp * 128];
        m[0] = fmaxf(m[0], v[0]);
        m[1] = fmaxf(m[1], v[1]);
        m[2] = fmaxf(m[2], v[2]);
        m[3] = fmaxf(m[3], v[3]);
    }
#pragma unroll
    for (int pp = 0; pp < 32; ++pp)
        *(f32x4*)&base[pp * 128 + 64] = m;
}

extern "C" void kernel_launch(void* const* d_in, const int* in_sizes, int n_in,
                              void* d_out, int out_size, void* d_ws, size_t ws_size,
                              hipStream_t stream) {
    const float* x     = (const float*)d_in[0];
    const float* lw    = (const float*)d_in[1];
    const float* bw    = (const float*)d_in[2];
    const float* sw    = (const float*)d_in[3];
    const float* ss    = (const float*)d_in[4];
    const float* gamma = (const float*)d_in[5];
    const float* beta  = (const float*)d_in[6];
    const float* mean  = (const float*)d_in[7];
    const float* var   = (const float*)d_in[8];
    float* out = (float*)d_out;

    const int N = in_sizes[0] / IN_FEAT;
    const int nbx = (N + BM1 - 1) / BM1;
    const size_t w_bytes = (size_t)OUT_FEAT * KTOT * sizeof(bf16);
    const size_t a_bytes = (size_t)nbx * BM1 * KTOT * sizeof(bf16);

    if (ws_size >= A_OFF + a_bytes) {
        bf16* W = (bf16*)d_ws;
        bf16* A = (bf16*)((char*)d_ws + A_OFF);
        prep_w<<<(OUT_FEAT * (KTOT / 8) + 255) / 256, 256, 0, stream>>>(bw, sw, ss, W);
        const int total8 = N * (IN_FEAT / 8);
        prep_a<<<(total8 + 255) / 256, 256, 0, stream>>>(x, A, total8);
        const int supers = (nbx + 31) / 32;
        pfn_gemm_ws<<<supers * 256, 1024, 0, stream>>>(x, A, W, lw, gamma, beta,
                                                       mean, var, out, N, nbx);
    } else if (ws_size >= w_bytes) {
        bf16* W = (bf16*)d_ws;
        prep_w<<<(OUT_FEAT * (KTOT / 8) + 255) / 256, 256, 0, stream>>>(bw, sw, ss, W);
        pfn_gemm<true><<<dim3((N + BM - 1) / BM, OUT_FEAT / BN), 256, 0, stream>>>(
            x, W, bw, sw, ss, lw, gamma, beta, mean, var, out, N);
    } else {
        pfn_gemm<false><<<dim3((N + BM - 1) / BM, OUT_FEAT / BN), 256, 0, stream>>>(
            x, nullptr, bw, sw, ss, lw, gamma, beta, mean, var, out, N);
    }
    pfn_maxcat<<<(N + 15) / 16, 256, 0, stream>>>(out, N);
}